// Round 3
// baseline (892.407 us; speedup 1.0000x reference)
//
#include <hip/hip_runtime.h>

// LinearMPC PGD, round 8: R5 tier split + STATIC ping-pong dbuf (unroll-by-2).
// 128 blocks x 512 thr (8 waves, 2/SIMD, <=256 unified regs/wave).
// Wave w owns cols [w*64,+64) = 4 MFMA n-tiles:
//   T0,T1: bf16 B-fragments in registers (128 regs)
//   T2:    H rows fully in LDS (128 rows x 512, XOR-swizzled, 128 KB, iter-invariant)
//   T3:    ks 0..7 in registers (32 regs), ks 8..15 streamed from L2 (depth-2, as R5)
// u exchange: ub0/ub1 FIXED arrays, loop unrolled by 2 -> compile-time alternation,
//   ONE __syncthreads per iteration, no runtime LDS pointer swap.
// Hypothesis from R6/R7 post-mortem: the regression was the loop-carried pointer
//   swap defeating static LDS addressing/scheduling (FETCH/WRITE_SIZE rose with
//   latency-bound counters), NOT the single barrier itself. Conflict counter is
//   exactly proportional to b128 read count in R5/R6/R7 -> swizzle is bank-neutral.
// Lessons: R2 no cross-block comm; R3 256-reg cap; R4 pipes partially overlap;
// R5 LDS traffic row-count-invariant; R6 keep stream <= 8 loads/wave/iter;
// R7 swizzle == padding for conflicts.

typedef unsigned short u16t;
typedef __attribute__((ext_vector_type(8))) short short8;
typedef __attribute__((ext_vector_type(4))) float floatx4;

#define HLDS_BYTES (128 * 512 * 2)                 // 131,072
#define UBF_BYTES  (16 * 512 * 2)                  // 16,384
#define DYN_LDS    (HLDS_BYTES + 2 * UBF_BYTES)    // 163,840 == 160 KiB exactly

__device__ __forceinline__ u16t f32_to_bf16(float x) {
    unsigned int u = __builtin_bit_cast(unsigned int, x);
    u = (u + 0x7FFFu + ((u >> 16) & 1u)) >> 16;   // RNE
    return (u16t)u;
}

__global__ void convert_H_bf16(const float* __restrict__ H, u16t* __restrict__ Hb) {
    int idx = blockIdx.x * 256 + threadIdx.x;   // 1024 x 256 = 262144
    Hb[idx] = f32_to_bf16(H[idx]);
}

#define MFMA(a, b, c) __builtin_amdgcn_mfma_f32_16x16x32_bf16((a), (b), (c), 0, 0, 0)

__global__ __launch_bounds__(512, 2)
void pgd_kernel8(const float* __restrict__ xref,   // [2048][65][8]
                 const float* __restrict__ H,      // [512][512] fp32
                 const u16t*  __restrict__ Hb,     // [512][512] bf16
                 const float* __restrict__ Phi,    // [65][8][8]
                 const float* __restrict__ Q,      // [8][8]
                 float* __restrict__ out)          // [2048][512]
{
    extern __shared__ __align__(16) char smem[];
    u16t* Hlds = (u16t*)smem;                          // [128][512], granule-swizzled
    u16t* ub0  = (u16t*)(smem + HLDS_BYTES);           // [16][512],  granule-swizzled
    u16t* ub1  = (u16t*)(smem + HLDS_BYTES + UBF_BYTES);

    const int tid  = threadIdx.x;
    const int lane = tid & 63;
    const int w    = tid >> 6;        // wave 0..7
    const int quad = lane >> 4;       // 0..3
    const int lcol = lane & 15;       // 0..15
    const int b0   = blockIdx.x * 16;
    const int colbase = w * 64;

    // ---- stage T2 H-rows into LDS (swizzled):
    //      ldsrow r holds H[(r>>4)*64 + 32 + (r&15)]; granule g stored at g^(r&7) ----
    for (int e = tid; e < 8192; e += 512) {
        int r = e >> 6, g = e & 63;
        *(short8*)&Hlds[r * 512 + ((g ^ (r & 7)) << 3)] =
            *(const short8*)&Hb[(long)((r >> 4) * 64 + 32 + (r & 15)) * 512 + g * 8];
    }
    // ---- zero both u buffers (contiguous, 16B vector stores) ----
    {
        short8 z8 = (short8){0,0,0,0,0,0,0,0};
        short8* ub = (short8*)ub0;             // 2 * 16 * 512 shorts = 2048 granules
        for (int e = tid; e < 2048; e += 512) ub[e] = z8;
    }

    // ---- f (linear term) + u master, per-thread regs, C/D layout ----
    float f_reg[4][4], u_reg[4][4];
    #pragma unroll
    for (int T = 0; T < 4; ++T) {
        int c = colbase + T * 16 + lcol;
        int k = c >> 3, i = c & 7;
        #pragma unroll
        for (int r = 0; r < 4; ++r) {
            int m = quad * 4 + r;
            const float* xr = xref + (long)(b0 + m) * 520;
            float s = 0.f;
            #pragma unroll
            for (int j = 0; j < 8; ++j) {
                float z = 0.f;
                #pragma unroll
                for (int l = 0; l < 8; ++l) z += Q[j * 8 + l] * (xr[k * 8 + l] - xr[l]);
                s += Phi[k * 64 + i * 8 + j] * z;
            }
            f_reg[T][r] = -2.0f * s;
            u_reg[T][r] = 0.0f;
        }
    }

    // ---- register B-fragments: T0,T1 full (128 regs) ----
    short8 hfragA[2][16];
    #pragma unroll
    for (int t = 0; t < 2; ++t) {
        const float* hrow = H + (long)(colbase + t * 16 + lcol) * 512;
        #pragma unroll
        for (int ks = 0; ks < 16; ++ks) {
            const float* hp = hrow + ks * 32 + quad * 8;
            short8 fr;
            #pragma unroll
            for (int j = 0; j < 8; ++j) fr[j] = (short)f32_to_bf16(hp[j]);
            hfragA[t][ks] = fr;
        }
    }
    // ---- register B-fragments: T3 ks 0..7 (32 regs) ----
    short8 frag3[8];
    {
        const float* hrow = H + (long)(colbase + 48 + lcol) * 512;
        #pragma unroll
        for (int ks = 0; ks < 8; ++ks) {
            const float* hp = hrow + ks * 32 + quad * 8;
            short8 fr;
            #pragma unroll
            for (int j = 0; j < 8; ++j) fr[j] = (short)f32_to_bf16(hp[j]);
            frag3[ks] = fr;
        }
    }
    __syncthreads();

    // streamed half of T3: ks 8..15 of row (colbase+48+lcol), iteration-invariant.
    // depth-2 rolling prefetch, exactly as the proven R5 schedule.
    const u16t* hb3 = Hb + (long)(colbase + 48 + lcol) * 512;
    short8 sb0 = *(const short8*)&hb3[8 * 32 + quad * 8];
    short8 sb1 = *(const short8*)&hb3[9 * 32 + quad * 8];

    // per-thread LDS read bases; swizzle offset in shorts: (g<<3) ^ swz, swz=(lcol&7)<<3
    const int  swz = (lcol & 7) << 3;
    const u16t* h2 = &Hlds[(w * 16 + lcol) * 512];

// one logical PGD iteration: read u from RB (static symbol), write new u to WB.
// Single barrier at the end: WB visible for next half; next half's writes to RB
// cannot start before this barrier, so RB reads here are safe. 100 = 50 pairs.
#define PGD_BODY(RB, WB)                                                         \
  {                                                                              \
    const u16t* ar = &RB[lcol * 512];                                            \
    floatx4 acc[4];                                                              \
    _Pragma("unroll")                                                            \
    for (int T = 0; T < 4; ++T) acc[T] = (floatx4){0.f, 0.f, 0.f, 0.f};          \
    _Pragma("unroll")                                                            \
    for (int ks = 0; ks < 8; ++ks) {                                             \
        int goff = (((ks * 4 + quad) << 3) ^ swz);                               \
        short8 a  = *(const short8*)&ar[goff];                                   \
        short8 b2 = *(const short8*)&h2[goff];                                   \
        acc[0] = MFMA(a, hfragA[0][ks], acc[0]);                                 \
        acc[1] = MFMA(a, hfragA[1][ks], acc[1]);                                 \
        acc[2] = MFMA(a, b2, acc[2]);                                            \
        acc[3] = MFMA(a, frag3[ks], acc[3]);                                     \
    }                                                                            \
    _Pragma("unroll")                                                            \
    for (int ks = 8; ks < 16; ++ks) {                                            \
        int goff = (((ks * 4 + quad) << 3) ^ swz);                               \
        short8 a  = *(const short8*)&ar[goff];                                   \
        short8 b2 = *(const short8*)&h2[goff];                                   \
        short8 b3 = sb0;                                                         \
        sb0 = sb1;                                                               \
        sb1 = *(const short8*)&hb3[(8 + ((ks - 6) & 7)) * 32 + quad * 8];        \
        acc[0] = MFMA(a, hfragA[0][ks], acc[0]);                                 \
        acc[1] = MFMA(a, hfragA[1][ks], acc[1]);                                 \
        acc[2] = MFMA(a, b2, acc[2]);                                            \
        acc[3] = MFMA(a, b3, acc[3]);                                            \
    }                                                                            \
    _Pragma("unroll")                                                            \
    for (int T = 0; T < 4; ++T) {                                                \
        int c = colbase + T * 16 + lcol;                                         \
        _Pragma("unroll")                                                        \
        for (int r = 0; r < 4; ++r) {                                            \
            float g  = acc[T][r] + f_reg[T][r];                                  \
            float un = u_reg[T][r] - 0.01f * g;                                  \
            un = fminf(1.0f, fmaxf(-1.0f, un));                                  \
            u_reg[T][r] = un;                                                    \
            int m = quad * 4 + r;                                                \
            WB[m * 512 + (((c >> 3) ^ (m & 7)) << 3) + (c & 7)] = f32_to_bf16(un); \
        }                                                                        \
    }                                                                            \
    __syncthreads();                                                             \
  }

    for (int it = 0; it < 50; ++it) {
        PGD_BODY(ub0, ub1);
        PGD_BODY(ub1, ub0);
    }
#undef PGD_BODY

    // ---- write final u (fp32) ----
    #pragma unroll
    for (int T = 0; T < 4; ++T) {
        int c = colbase + T * 16 + lcol;
        #pragma unroll
        for (int r = 0; r < 4; ++r)
            out[(long)(b0 + quad * 4 + r) * 512 + c] = u_reg[T][r];
    }
}

extern "C" void kernel_launch(void* const* d_in, const int* in_sizes, int n_in,
                              void* d_out, int out_size, void* d_ws, size_t ws_size,
                              hipStream_t stream) {
    // inputs: 0=x0 (unused), 1=xref, 2=H, 3=Phi, 4=Q
    const float* xref = (const float*)d_in[1];
    const float* H    = (const float*)d_in[2];
    const float* Phi  = (const float*)d_in[3];
    const float* Q    = (const float*)d_in[4];
    u16t* Hb = (u16t*)d_ws;                      // 512 KB

    (void)hipFuncSetAttribute((const void*)pgd_kernel8,
                              hipFuncAttributeMaxDynamicSharedMemorySize, DYN_LDS);

    convert_H_bf16<<<1024, 256, 0, stream>>>(H, Hb);
    pgd_kernel8<<<128, 512, DYN_LDS, stream>>>(xref, H, Hb, Phi, Q, (float*)d_out);
}

// Round 4
// 252.949 us; speedup vs baseline: 3.5280x; 3.5280x over previous
//
#include <hip/hip_runtime.h>

// LinearMPC PGD, round 9: EXACT R5 structure + depth-8 hoisted stream prefetch.
// 128 blocks x 512 thr (8 waves, 2/SIMD, <=256 unified regs/wave).
// Wave w owns cols [w*64,+64) = 4 MFMA n-tiles:
//   T0,T1: bf16 B-fragments in registers (128 regs)
//   T2:    H rows in LDS (128 rows x 520-pad, 133 KB, iteration-invariant)
//   T3:    ks 0..7 in registers (32 regs), ks 8..15 streamed from L2,
//          ALL 8 loads issued at iteration top (sb[8]), consumed in ks 8..15
//          -> ~350 cy of ks0..7 LDS+MFMA covers ~200 cy L2 latency (was depth-2, ~90 cy).
// Two barriers per iteration, single u buffer — UNCHANGED from the 206 us R5.
// Lessons: R2 no cross-block comm; R3 256-reg cap (spill => WRITE_SIZE blowup);
// R4 pipes partially overlap; R5 LDS traffic row-count-invariant;
// R6 stream <= 8 loads/wave/iter; R7 swizzle == padding for conflicts (4cy/b128
// replay is structural); R8 dbuf/single-barrier family dead (codegen fragility:
// any restructuring near the register ceiling triggers spill/remat, FETCH blowup).

typedef unsigned short u16t;
typedef __attribute__((ext_vector_type(8))) short short8;
typedef __attribute__((ext_vector_type(4))) float floatx4;

#define HLDS_BYTES (128 * 520 * 2)                 // 133,120
#define UBF_BYTES  (16 * 520 * 2)                  // 16,640
#define DYN_LDS    (HLDS_BYTES + UBF_BYTES)        // 149,760 < 160 KiB

__device__ __forceinline__ u16t f32_to_bf16(float x) {
    unsigned int u = __builtin_bit_cast(unsigned int, x);
    u = (u + 0x7FFFu + ((u >> 16) & 1u)) >> 16;   // RNE
    return (u16t)u;
}

__global__ void convert_H_bf16(const float* __restrict__ H, u16t* __restrict__ Hb) {
    int idx = blockIdx.x * 256 + threadIdx.x;   // 1024 x 256 = 262144
    Hb[idx] = f32_to_bf16(H[idx]);
}

#define MFMA(a, b, c) __builtin_amdgcn_mfma_f32_16x16x32_bf16((a), (b), (c), 0, 0, 0)

__global__ __launch_bounds__(512, 2)
void pgd_kernel9(const float* __restrict__ xref,   // [2048][65][8]
                 const float* __restrict__ H,      // [512][512] fp32
                 const u16t*  __restrict__ Hb,     // [512][512] bf16
                 const float* __restrict__ Phi,    // [65][8][8]
                 const float* __restrict__ Q,      // [8][8]
                 float* __restrict__ out)          // [2048][512]
{
    extern __shared__ __align__(16) char smem[];
    u16t* Hlds = (u16t*)smem;                               // [128][520]
    u16t (*u_bf)[520] = (u16t(*)[520])(smem + HLDS_BYTES);  // [16][520]

    const int tid  = threadIdx.x;
    const int lane = tid & 63;
    const int w    = tid >> 6;        // wave 0..7
    const int quad = lane >> 4;       // 0..3
    const int lcol = lane & 15;       // 0..15
    const int b0   = blockIdx.x * 16;
    const int colbase = w * 64;

    // ---- stage T2 H-rows into LDS: ldsrow r holds H[(r>>4)*64 + 32 + (r&15)] ----
    for (int e = tid; e < 8192; e += 512) {
        int r = e >> 6, c = e & 63;
        *(short8*)&Hlds[r * 520 + c * 8] =
            *(const short8*)&Hb[(long)((r >> 4) * 64 + 32 + (r & 15)) * 512 + c * 8];
    }
    // ---- zero u_bf ----
    {
        u16t* ub = &u_bf[0][0];
        for (int e = tid; e < 8320; e += 512) ub[e] = 0;
    }

    // ---- register B-fragments: T0,T1 full (128 regs) ----
    short8 hfragA[2][16];
    #pragma unroll
    for (int t = 0; t < 2; ++t) {
        const float* hrow = H + (long)(colbase + t * 16 + lcol) * 512;
        #pragma unroll
        for (int ks = 0; ks < 16; ++ks) {
            const float* hp = hrow + ks * 32 + quad * 8;
            short8 fr;
            #pragma unroll
            for (int j = 0; j < 8; ++j) fr[j] = (short)f32_to_bf16(hp[j]);
            hfragA[t][ks] = fr;
        }
    }
    // ---- register B-fragments: T3 ks 0..7 (32 regs) ----
    short8 frag3[8];
    {
        const float* hrow = H + (long)(colbase + 48 + lcol) * 512;
        #pragma unroll
        for (int ks = 0; ks < 8; ++ks) {
            const float* hp = hrow + ks * 32 + quad * 8;
            short8 fr;
            #pragma unroll
            for (int j = 0; j < 8; ++j) fr[j] = (short)f32_to_bf16(hp[j]);
            frag3[ks] = fr;
        }
    }

    // ---- f (linear term) + u master, per-thread regs, C/D layout ----
    float f_reg[4][4], u_reg[4][4];
    #pragma unroll
    for (int T = 0; T < 4; ++T) {
        int c = colbase + T * 16 + lcol;
        int k = c >> 3, i = c & 7;
        #pragma unroll
        for (int r = 0; r < 4; ++r) {
            int m = quad * 4 + r;
            const float* xr = xref + (long)(b0 + m) * 520;
            float s = 0.f;
            #pragma unroll
            for (int j = 0; j < 8; ++j) {
                float z = 0.f;
                #pragma unroll
                for (int l = 0; l < 8; ++l) z += Q[j * 8 + l] * (xr[k * 8 + l] - xr[l]);
                s += Phi[k * 64 + i * 8 + j] * z;
            }
            f_reg[T][r] = -2.0f * s;
            u_reg[T][r] = 0.0f;
        }
    }
    __syncthreads();

    // streamed half of T3: ks 8..15 of row (colbase+48+lcol), iteration-invariant
    const u16t* hb3 = Hb + (long)(colbase + 48 + lcol) * 512;
    const u16t* h2  = Hlds + (w * 16 + lcol) * 520;

    for (int it = 0; it < 100; ++it) {
        // ---- issue ALL 8 streamed loads for ks 8..15 (L2-hot, in flight
        //      under the whole ks0..7 phase) ----
        short8 sb[8];
        #pragma unroll
        for (int p = 0; p < 8; ++p)
            sb[p] = *(const short8*)&hb3[(8 + p) * 32 + quad * 8];

        floatx4 acc[4];
        #pragma unroll
        for (int T = 0; T < 4; ++T) acc[T] = (floatx4){0.f, 0.f, 0.f, 0.f};

        // ---- ks 0..7: all-register T3 ----
        #pragma unroll
        for (int ks = 0; ks < 8; ++ks) {
            short8 a  = *(const short8*)&u_bf[lcol][ks * 32 + quad * 8];
            short8 b2 = *(const short8*)&h2[ks * 32 + quad * 8];
            acc[0] = MFMA(a, hfragA[0][ks], acc[0]);
            acc[1] = MFMA(a, hfragA[1][ks], acc[1]);
            acc[2] = MFMA(a, b2, acc[2]);
            acc[3] = MFMA(a, frag3[ks], acc[3]);
        }
        // ---- ks 8..15: streamed T3 from sb[] (static indices) ----
        #pragma unroll
        for (int ks = 8; ks < 16; ++ks) {
            short8 a  = *(const short8*)&u_bf[lcol][ks * 32 + quad * 8];
            short8 b2 = *(const short8*)&h2[ks * 32 + quad * 8];
            acc[0] = MFMA(a, hfragA[0][ks], acc[0]);
            acc[1] = MFMA(a, hfragA[1][ks], acc[1]);
            acc[2] = MFMA(a, b2, acc[2]);
            acc[3] = MFMA(a, sb[ks - 8], acc[3]);
        }

        // ---- update u master ----
        #pragma unroll
        for (int T = 0; T < 4; ++T)
            #pragma unroll
            for (int r = 0; r < 4; ++r) {
                float g  = acc[T][r] + f_reg[T][r];
                float un = u_reg[T][r] - 0.01f * g;
                un = fminf(1.0f, fmaxf(-1.0f, un));
                u_reg[T][r] = un;
            }

        __syncthreads();   // all waves done reading old u_bf
        #pragma unroll
        for (int T = 0; T < 4; ++T) {
            int c = colbase + T * 16 + lcol;
            #pragma unroll
            for (int r = 0; r < 4; ++r)
                u_bf[quad * 4 + r][c] = f32_to_bf16(u_reg[T][r]);
        }
        __syncthreads();   // new u_bf visible
    }

    // ---- write final u (fp32) ----
    #pragma unroll
    for (int T = 0; T < 4; ++T) {
        int c = colbase + T * 16 + lcol;
        #pragma unroll
        for (int r = 0; r < 4; ++r)
            out[(long)(b0 + quad * 4 + r) * 512 + c] = u_reg[T][r];
    }
}

extern "C" void kernel_launch(void* const* d_in, const int* in_sizes, int n_in,
                              void* d_out, int out_size, void* d_ws, size_t ws_size,
                              hipStream_t stream) {
    // inputs: 0=x0 (unused), 1=xref, 2=H, 3=Phi, 4=Q
    const float* xref = (const float*)d_in[1];
    const float* H    = (const float*)d_in[2];
    const float* Phi  = (const float*)d_in[3];
    const float* Q    = (const float*)d_in[4];
    u16t* Hb = (u16t*)d_ws;                      // 512 KB

    (void)hipFuncSetAttribute((const void*)pgd_kernel9,
                              hipFuncAttributeMaxDynamicSharedMemorySize, DYN_LDS);

    convert_H_bf16<<<1024, 256, 0, stream>>>(H, Hb);
    pgd_kernel9<<<128, 512, DYN_LDS, stream>>>(xref, H, Hb, Phi, Q, (float*)d_out);
}